// Round 18
// baseline (209.749 us; speedup 1.0000x reference)
//
#include <hip/hip_runtime.h>
#include <hip/hip_fp16.h>

typedef __attribute__((ext_vector_type(8))) _Float16 half8;
typedef __attribute__((ext_vector_type(4))) float f32x4;

namespace {
constexpr int B_G = 131072;     // graphs
constexpr int P   = 22;
constexpr int F   = 14;
constexpr int NF  = 308;        // P*F
constexpr long long N_NODES = (long long)B_G * P;   // 2883584

constexpr int G     = 48;       // graphs per tile
constexpr int TILES = (B_G + G - 1) / G;   // 2731
constexpr int NBLKP = 512;      // persistent blocks (2/CU)

constexpr int KS1 = 10;         // ceil(308/32)
constexpr int KS2 = 8;          // 256/32
constexpr int KS3 = 4;          // 128/32
constexpr int JT1 = 16;         // 256/16
constexpr int JT2 = 8;          // 128/16
constexpr int JT3 = 2;          // 22 -> pad 32

// d_ws byte offsets; single-term fp16 weights, MFMA B-fragment order (1KB/fragment)
constexpr int W1F = 0;
constexpr int W2F = W1F + KS1 * JT1 * 1024;   // 163840
constexpr int W3F = W2F + KS2 * JT2 * 1024;   // 229376
constexpr int STARTS_OFF = W3F + KS3 * JT3 * 1024;  // 237568 ; (B_G+G+1) ints
constexpr int CVT_DWORDS = (KS1*JT1 + KS2*JT2 + KS3*JT3) * 256;  // 59392
constexpr int CVT_BLKS  = (CVT_DWORDS + 255) / 256;              // 232
constexpr int SCAN_BLKS = (int)((N_NODES + 255) / 256);          // 11264

// LDS (ush): A1 dbuf = 2 x 15360 (KS1*4*G*8, k 308->320); A2 aliases A1[cur][0,12288);
// A3 = 6144 @30720. Total 36864 ush = 73728 B.
constexpr int A1SZ = 15360;
constexpr int A3O  = 30720;
}

__device__ __forceinline__ unsigned short f2h(float v) {
    __half h = __float2half(v);
    return *reinterpret_cast<unsigned short*>(&h);
}

// ---- aux: weight convert (blocks [0,CVT_BLKS)) + starts scan (rest) ----
__global__ void aux_kernel(const float* __restrict__ W1,
                           const float* __restrict__ W2,
                           const float* __restrict__ W3,
                           const int* __restrict__ batch,
                           unsigned* __restrict__ ws,
                           int* __restrict__ starts)
{
    const int blk = blockIdx.x;
    const int t   = threadIdx.x;
    if (blk < CVT_BLKS) {
        int p = blk * 256 + t;                    // dword index (2 fp16 elems)
        if (p >= CVT_DWORDS) return;
        const int n1 = KS1 * JT1 * 256;
        const int n2 = KS2 * JT2 * 256;
        const float* W; int NK, NJ, stride, JT, oB, pl;
        if (p < n1)            { W = W1; NK = NF;  NJ = 256; stride = NF;  JT = JT1; oB = W1F/4; pl = p; }
        else if (p < n1 + n2)  { W = W2; NK = 256; NJ = 128; stride = 256; JT = JT2; oB = W2F/4; pl = p - n1; }
        else                   { W = W3; NK = 128; NJ = 22;  stride = 128; JT = JT3; oB = W3F/4; pl = p - n1 - n2; }

        const int e2   = pl & 3;
        const int lane = (pl >> 2) & 63;
        const int jt   = (pl >> 8) % JT;
        const int ks   = (pl >> 8) / JT;
        const int j    = jt * 16 + (lane & 15);
        const int kb   = ks * 32 + (lane >> 4) * 8 + e2 * 2;

        unsigned d = 0;
        #pragma unroll
        for (int q = 0; q < 2; ++q) {
            const int k = kb + q;
            const float v = (k < NK && j < NJ) ? W[j * stride + k] : 0.0f;
            d |= (unsigned)f2h(v) << (16 * q);
        }
        ws[oB + pl] = d;
    } else {
        // starts[g] = lower_bound(batch, g); padded to B_G+G for ragged last tile.
        const long long i = (long long)(blk - CVT_BLKS) * 256 + t;
        if (i >= N_NODES) return;
        const int b  = batch[i];
        const int bp = (i == 0) ? -1 : batch[i - 1];
        for (int g = bp + 1; g <= b; ++g) starts[g] = (int)i;
        if (i == N_NODES - 1)
            for (int g = b + 1; g <= B_G + G; ++g) starts[g] = (int)N_NODES;
    }
}

#define MFMA16(A_, B_, C_) __builtin_amdgcn_mfma_f32_16x16x32_f16(A_, B_, C_, 0, 0, 0)

#define LOADB1(H_, KS_) { \
    _Pragma("unroll") for (int n = 0; n < 4; ++n) \
        H_[n] = *reinterpret_cast<const half8*>(&B1[((((KS_) * JT1) + (wv * 4 + n)) * 64 + lane) * 8]); }

#define COMP1(H_, KS_) { \
    half8 a_[3]; \
    _Pragma("unroll") for (int m = 0; m < 3; ++m) \
        a_[m] = *reinterpret_cast<const half8*>(&s_scr[abase + (((KS_) * 4 + kq) * G + (m * 16 + r16)) * 8]); \
    _Pragma("unroll") for (int n = 0; n < 4; ++n) \
        _Pragma("unroll") for (int m = 0; m < 3; ++m) \
            acc[m][n] = MFMA16(a_[m], H_[n], acc[m][n]); }

#define LOADB2(H_, KS_) { \
    _Pragma("unroll") for (int n = 0; n < 2; ++n) \
        H_[n] = *reinterpret_cast<const half8*>(&B2[((((KS_) * JT2) + (wv * 2 + n)) * 64 + lane) * 8]); }

#define COMP2(H_, KS_) { \
    half8 a_[3]; \
    _Pragma("unroll") for (int m = 0; m < 3; ++m) \
        a_[m] = *reinterpret_cast<const half8*>(&s_scr[abase + (((KS_) * 4 + kq) * G + (m * 16 + r16)) * 8]); \
    _Pragma("unroll") for (int n = 0; n < 2; ++n) \
        _Pragma("unroll") for (int m = 0; m < 3; ++m) \
            acc2[m][n] = MFMA16(a_[m], H_[n], acc2[m][n]); }

// slot-major immediate gather of one item into buffer base AB_ (prologue / tail item)
#define GSLOT_NOW(IT_, AB_, SBUF_) { \
    const int g_ = (IT_) / P, p_ = (IT_) - g_ * P; \
    const int s_ = SBUF_[g_], c_ = SBUF_[g_ + 1] - s_; \
    const bool lv_ = (p_ < c_); \
    const float2* xr_ = reinterpret_cast<const float2*>(x + (size_t)(s_ + p_) * F); \
    _Pragma("unroll") for (int q = 0; q < 7; ++q) { \
        float2 v = make_float2(0.f, 0.f); \
        if (lv_) v = xr_[q]; \
        const int k = p_ * F + q * 2; \
        const unsigned d = (unsigned)f2h(v.x) | ((unsigned)f2h(v.y) << 16); \
        *reinterpret_cast<unsigned*>(&s_scr[(AB_) + (((k >> 5) * 4 + ((k >> 3) & 3)) * G + g_) * 8 + (k & 7)]) = d; \
    } }

// ---- fused persistent: tiles pipelined (stage-load T+1 under GEMM(T)) ----
__global__ __launch_bounds__(256, 2)
void mlp_mfma_kernel(const float* __restrict__ x,
                     const float* __restrict__ b1,
                     const float* __restrict__ b2,
                     const float* __restrict__ b3,
                     const unsigned short* __restrict__ ws,
                     const int* __restrict__ starts,
                     float* __restrict__ out)
{
    __shared__ __align__(16) unsigned short s_scr[36864];   // 73728 B
    __shared__ float s_b1[256], s_b2[128], s_b3[32];
    __shared__ int s_st[2][G + 1];

    const int t    = threadIdx.x;
    const int lane = t & 63;
    const int wv   = t >> 6;          // 0..3
    const int r16  = lane & 15;
    const int kq   = lane >> 4;       // 0..3

    s_b1[t] = b1[t];
    if (t < 128) s_b2[t] = b2[t];
    if (t < 32)  s_b3[t] = (t < 22) ? b3[t] : 0.0f;

    const unsigned short* B1 = ws + W1F / 2;
    const unsigned short* B2 = ws + W2F / 2;
    const unsigned short* B3 = ws + W3F / 2;

    // ---- prologue: ks9 dead cells (k>=308, never gathered) zeroed once per buffer ----
    // dead cells: rows (9*4+2)[elems 4..7] and (9*4+3)[all] per graph, both buffers.
    if (t < 96) {        // 2 bufs * 48 graphs
        const int c = t / 48, g = t % 48;
        const int b38 = c * A1SZ + ((9 * 4 + 2) * G + g) * 8;
        const int b39 = c * A1SZ + ((9 * 4 + 3) * G + g) * 8;
        *reinterpret_cast<uint2*>(&s_scr[b38 + 4]) = make_uint2(0u, 0u);
        *reinterpret_cast<uint2*>(&s_scr[b39])     = make_uint2(0u, 0u);
        *reinterpret_cast<uint2*>(&s_scr[b39 + 4]) = make_uint2(0u, 0u);
    }

    int tile = blockIdx.x;
    int cur  = 0;
    if (t <= G) s_st[0][t] = starts[tile * G + t];
    __syncthreads();

    // immediate gather of the first tile into A1[0] (slot-major, fixed 1056 items)
    GSLOT_NOW(t,       0, s_st[0])
    GSLOT_NOW(t + 256, 0, s_st[0])
    GSLOT_NOW(t + 512, 0, s_st[0])
    GSLOT_NOW(t + 768, 0, s_st[0])
    if (t < 32) GSLOT_NOW(t + 1024, 0, s_st[0])

    for (; tile < TILES; tile += NBLKP) {
        const int  g0    = tile * G;
        const int  tileN = tile + NBLKP;
        const bool hasN  = (tileN < TILES);
        const int  nxt   = cur ^ 1;
        const int  abase = cur * A1SZ;
        const int  nbase = nxt * A1SZ;

        half8 Ba[4], Bb[4], Bc[4];
        LOADB1(Ba, 0)
        LOADB1(Bb, 1)
        LOADB1(Bc, 2)
        if (hasN && t <= G) s_st[nxt][t] = starts[tileN * G + t];
        __syncthreads();   // A1[cur] gather + s_st[nxt] visible; orders prev GEMM3 A3 reads

        // ---- stage-issue x loads for tile T+1 (slot-major; latency hides under GEMM1) ----
        float2 xv[4][7];
        int gu[4], pu[4];
        if (hasN) {
            const int* sn = s_st[nxt];
            #pragma unroll
            for (int u = 0; u < 4; ++u) {
                const int it = t + u * 256;
                const int g_ = it / P, p_ = it - g_ * P;
                gu[u] = g_; pu[u] = p_;
                const int s_ = sn[g_], c_ = sn[g_ + 1] - s_;
                const bool lv = (p_ < c_);
                const float2* xr = reinterpret_cast<const float2*>(x + (size_t)(s_ + p_) * F);
                #pragma unroll
                for (int q = 0; q < 7; ++q) {
                    xv[u][q] = make_float2(0.f, 0.f);
                    if (lv) xv[u][q] = xr[q];
                }
            }
        }

        // ---- GEMM1: [48 x 308] x [308 x 256]; depth-3 B pipeline ----
        f32x4 acc[3][4];
        #pragma unroll
        for (int m = 0; m < 3; ++m)
            #pragma unroll
            for (int n = 0; n < 4; ++n) acc[m][n] = (f32x4){0.f, 0.f, 0.f, 0.f};

        COMP1(Ba, 0)  LOADB1(Ba, 3)
        COMP1(Bb, 1)  LOADB1(Bb, 4)
        COMP1(Bc, 2)  LOADB1(Bc, 5)
        COMP1(Ba, 3)  LOADB1(Ba, 6)
        COMP1(Bb, 4)  LOADB1(Bb, 7)
        COMP1(Bc, 5)  LOADB1(Bc, 8)
        COMP1(Ba, 6)  LOADB1(Ba, 9)
        COMP1(Bb, 7)

        half8 Ca[2], Cb[2], Cc[2];
        LOADB2(Ca, 0)
        LOADB2(Cb, 1)
        LOADB2(Cc, 2)
        COMP1(Bc, 8)
        COMP1(Ba, 9)
        __syncthreads();   // A1[cur] reads done before A2 overwrite

        // epilogue 1: bias+relu -> fp16 -> A2 tiled (@abase, aliases dead A1[cur])
        #pragma unroll
        for (int n = 0; n < 4; ++n) {
            const int j = (wv * 4 + n) * 16 + r16;
            const float bb = s_b1[j];
            const int base = abase + (((j >> 5) * 4 + ((j >> 3) & 3)) * G) * 8 + (j & 7);
            #pragma unroll
            for (int m = 0; m < 3; ++m)
                #pragma unroll
                for (int r = 0; r < 4; ++r) {
                    const int g = m * 16 + kq * 4 + r;
                    s_scr[base + g * 8] = f2h(fmaxf(acc[m][n][r] + bb, 0.0f));
                }
        }
        __syncthreads();

        // ---- stage-write tile T+1 into A1[nxt] (data arrived during GEMM1; no stall) ----
        if (hasN) {
            #pragma unroll
            for (int u = 0; u < 4; ++u) {
                #pragma unroll
                for (int q = 0; q < 7; ++q) {
                    const int k = pu[u] * F + q * 2;
                    const unsigned d = (unsigned)f2h(xv[u][q].x) | ((unsigned)f2h(xv[u][q].y) << 16);
                    *reinterpret_cast<unsigned*>(
                        &s_scr[nbase + (((k >> 5) * 4 + ((k >> 3) & 3)) * G + gu[u]) * 8 + (k & 7)]) = d;
                }
            }
            if (t < 32) GSLOT_NOW(t + 1024, nbase, s_st[nxt])   // items 1024..1055 immediate
        }

        // ---- GEMM2: [48 x 256] x [256 x 128]; depth-3 ----
        f32x4 acc2[3][2];
        #pragma unroll
        for (int m = 0; m < 3; ++m)
            #pragma unroll
            for (int n = 0; n < 2; ++n) acc2[m][n] = (f32x4){0.f, 0.f, 0.f, 0.f};

        COMP2(Ca, 0)  LOADB2(Ca, 3)
        COMP2(Cb, 1)  LOADB2(Cb, 4)
        COMP2(Cc, 2)  LOADB2(Cc, 5)
        COMP2(Ca, 3)  LOADB2(Ca, 6)
        COMP2(Cb, 4)  LOADB2(Cb, 7)
        COMP2(Cc, 5)
        COMP2(Ca, 6)

        half8 D3[8];
        #pragma unroll
        for (int ks = 0; ks < KS3; ++ks)
            #pragma unroll
            for (int n = 0; n < 2; ++n)
                D3[ks * 2 + n] = *reinterpret_cast<const half8*>(&B3[((ks * JT3 + n) * 64 + lane) * 8]);
        COMP2(Cb, 7)

        // epilogue 2: bias+relu -> fp16 -> A3 @A3O
        #pragma unroll
        for (int n = 0; n < 2; ++n) {
            const int j = (wv * 2 + n) * 16 + r16;
            const float bb = s_b2[j];
            const int base = A3O + (((j >> 5) * 4 + ((j >> 3) & 3)) * G) * 8 + (j & 7);
            #pragma unroll
            for (int m = 0; m < 3; ++m)
                #pragma unroll
                for (int r = 0; r < 4; ++r) {
                    const int g = m * 16 + kq * 4 + r;
                    s_scr[base + g * 8] = f2h(fmaxf(acc2[m][n][r] + bb, 0.0f));
                }
        }
        __syncthreads();   // A3 + A1[nxt] stage-writes visible

        // ---- GEMM3: [48 x 128] x [128 x 22(pad32)]; waves 0..2 ----
        if (wv < 3) {
            f32x4 acc3[2];
            acc3[0] = (f32x4){0.f, 0.f, 0.f, 0.f};
            acc3[1] = (f32x4){0.f, 0.f, 0.f, 0.f};
            const int mg = wv * 16;
            #pragma unroll
            for (int ks = 0; ks < KS3; ++ks) {
                const half8 a = *reinterpret_cast<const half8*>(
                    &s_scr[A3O + ((ks * 4 + kq) * G + (mg + r16)) * 8]);
                #pragma unroll
                for (int n = 0; n < 2; ++n)
                    acc3[n] = MFMA16(a, D3[ks * 2 + n], acc3[n]);
            }
            #pragma unroll
            for (int n = 0; n < 2; ++n) {
                const int j = n * 16 + r16;
                if (j < P) {
                    const float bb = s_b3[j];
                    #pragma unroll
                    for (int r = 0; r < 4; ++r) {
                        const int g = mg + kq * 4 + r;
                        if (g0 + g < B_G)
                            out[(size_t)(g0 + g) * P + j] = acc3[n][r] + bb;
                    }
                }
            }
        }
        cur = nxt;
    }
}

extern "C" void kernel_launch(void* const* d_in, const int* in_sizes, int n_in,
                              void* d_out, int out_size, void* d_ws, size_t ws_size,
                              hipStream_t stream) {
    const float* x     = (const float*)d_in[0];
    const int*   batch = (const int*)  d_in[1];
    const float* W1    = (const float*)d_in[2];
    const float* b1    = (const float*)d_in[3];
    const float* W2    = (const float*)d_in[4];
    const float* b2    = (const float*)d_in[5];
    const float* W3    = (const float*)d_in[6];
    const float* b3    = (const float*)d_in[7];
    float* out = (float*)d_out;
    int* starts = (int*)((char*)d_ws + STARTS_OFF);

    aux_kernel<<<dim3(CVT_BLKS + SCAN_BLKS), dim3(256), 0, stream>>>(
        W1, W2, W3, batch, (unsigned*)d_ws, starts);
    mlp_mfma_kernel<<<dim3(NBLKP), dim3(256), 0, stream>>>(
        x, b1, b2, b3, (const unsigned short*)d_ws, starts, out);
}

// Round 19
// 168.837 us; speedup vs baseline: 1.2423x; 1.2423x over previous
//
#include <hip/hip_runtime.h>
#include <hip/hip_fp16.h>

typedef __attribute__((ext_vector_type(8))) _Float16 half8;
typedef __attribute__((ext_vector_type(4))) float f32x4;

namespace {
constexpr int B_G = 131072;     // graphs
constexpr int P   = 22;
constexpr int F   = 14;
constexpr int NF  = 308;        // P*F
constexpr long long N_NODES = (long long)B_G * P;   // 2883584

constexpr int G     = 48;       // graphs per tile
constexpr int TILES = (B_G + G - 1) / G;   // 2731
constexpr int NBLKP = 512;      // persistent blocks (2/CU)

constexpr int KS1 = 10;         // ceil(308/32)
constexpr int KS2 = 8;          // 256/32
constexpr int KS3 = 4;          // 128/32
constexpr int JT1 = 16;         // 256/16
constexpr int JT2 = 8;          // 128/16
constexpr int JT3 = 2;          // 22 -> pad 32

// d_ws byte offsets; single-term fp16 weights, MFMA B-fragment order (1KB/fragment)
constexpr int W1F = 0;
constexpr int W2F = W1F + KS1 * JT1 * 1024;   // 163840
constexpr int W3F = W2F + KS2 * JT2 * 1024;   // 229376
constexpr int STARTS_OFF = W3F + KS3 * JT3 * 1024;  // 237568 ; (B_G+G+1) ints
constexpr int CVT_DWORDS = (KS1*JT1 + KS2*JT2 + KS3*JT3) * 256;  // 59392
constexpr int CVT_BLKS  = (CVT_DWORDS + 255) / 256;              // 232
constexpr int SCAN_BLKS = (int)((N_NODES + 255) / 256);          // 11264

// LDS (ush): A1 dbuf = 2 x 15360 (KS1*4*G*8, k 308->320); A2 aliases A1[cur][0,12288);
// A3 = 6144 @30720. Total 36864 ush = 73728 B.
constexpr int A1SZ = 15360;
constexpr int A3O  = 30720;
}

__device__ __forceinline__ unsigned short f2h(float v) {
    __half h = __float2half(v);
    return *reinterpret_cast<unsigned short*>(&h);
}

// ---- aux: weight convert (blocks [0,CVT_BLKS)) + starts scan (rest) ----
__global__ void aux_kernel(const float* __restrict__ W1,
                           const float* __restrict__ W2,
                           const float* __restrict__ W3,
                           const int* __restrict__ batch,
                           unsigned* __restrict__ ws,
                           int* __restrict__ starts)
{
    const int blk = blockIdx.x;
    const int t   = threadIdx.x;
    if (blk < CVT_BLKS) {
        int p = blk * 256 + t;                    // dword index (2 fp16 elems)
        if (p >= CVT_DWORDS) return;
        const int n1 = KS1 * JT1 * 256;
        const int n2 = KS2 * JT2 * 256;
        const float* W; int NK, NJ, stride, JT, oB, pl;
        if (p < n1)            { W = W1; NK = NF;  NJ = 256; stride = NF;  JT = JT1; oB = W1F/4; pl = p; }
        else if (p < n1 + n2)  { W = W2; NK = 256; NJ = 128; stride = 256; JT = JT2; oB = W2F/4; pl = p - n1; }
        else                   { W = W3; NK = 128; NJ = 22;  stride = 128; JT = JT3; oB = W3F/4; pl = p - n1 - n2; }

        const int e2   = pl & 3;
        const int lane = (pl >> 2) & 63;
        const int jt   = (pl >> 8) % JT;
        const int ks   = (pl >> 8) / JT;
        const int j    = jt * 16 + (lane & 15);
        const int kb   = ks * 32 + (lane >> 4) * 8 + e2 * 2;

        unsigned d = 0;
        #pragma unroll
        for (int q = 0; q < 2; ++q) {
            const int k = kb + q;
            const float v = (k < NK && j < NJ) ? W[j * stride + k] : 0.0f;
            d |= (unsigned)f2h(v) << (16 * q);
        }
        ws[oB + pl] = d;
    } else {
        // starts[g] = lower_bound(batch, g); padded to B_G+G for ragged last tile.
        const long long i = (long long)(blk - CVT_BLKS) * 256 + t;
        if (i >= N_NODES) return;
        const int b  = batch[i];
        const int bp = (i == 0) ? -1 : batch[i - 1];
        for (int g = bp + 1; g <= b; ++g) starts[g] = (int)i;
        if (i == N_NODES - 1)
            for (int g = b + 1; g <= B_G + G; ++g) starts[g] = (int)N_NODES;
    }
}

#define MFMA16(A_, B_, C_) __builtin_amdgcn_mfma_f32_16x16x32_f16(A_, B_, C_, 0, 0, 0)

#define LOADB1(H_, KS_) { \
    _Pragma("unroll") for (int n = 0; n < 4; ++n) \
        H_[n] = *reinterpret_cast<const half8*>(&B1[((((KS_) * JT1) + (wv * 4 + n)) * 64 + lane) * 8]); }

#define COMP1(H_, KS_) { \
    half8 a_[3]; \
    _Pragma("unroll") for (int m = 0; m < 3; ++m) \
        a_[m] = *reinterpret_cast<const half8*>(&s_scr[abase + (((KS_) * 4 + kq) * G + (m * 16 + r16)) * 8]); \
    _Pragma("unroll") for (int n = 0; n < 4; ++n) \
        _Pragma("unroll") for (int m = 0; m < 3; ++m) \
            acc[m][n] = MFMA16(a_[m], H_[n], acc[m][n]); }

#define LOADB2(H_, KS_) { \
    _Pragma("unroll") for (int n = 0; n < 2; ++n) \
        H_[n] = *reinterpret_cast<const half8*>(&B2[((((KS_) * JT2) + (wv * 2 + n)) * 64 + lane) * 8]); }

#define COMP2(H_, KS_) { \
    half8 a_[3]; \
    _Pragma("unroll") for (int m = 0; m < 3; ++m) \
        a_[m] = *reinterpret_cast<const half8*>(&s_scr[abase + (((KS_) * 4 + kq) * G + (m * 16 + r16)) * 8]); \
    _Pragma("unroll") for (int n = 0; n < 2; ++n) \
        _Pragma("unroll") for (int m = 0; m < 3; ++m) \
            acc2[m][n] = MFMA16(a_[m], H_[n], acc2[m][n]); }

// slot-major immediate gather of one item into buffer base AB_ (prologue / tail item)
#define GSLOT_NOW(IT_, AB_, SBUF_) { \
    const int g_ = (IT_) / P, p_ = (IT_) - g_ * P; \
    const int s_ = SBUF_[g_], c_ = SBUF_[g_ + 1] - s_; \
    const bool lv_ = (p_ < c_); \
    const float2* xr_ = reinterpret_cast<const float2*>(x + (size_t)(s_ + p_) * F); \
    _Pragma("unroll") for (int q = 0; q < 7; ++q) { \
        float2 v = make_float2(0.f, 0.f); \
        if (lv_) v = xr_[q]; \
        const int k = p_ * F + q * 2; \
        const unsigned d = (unsigned)f2h(v.x) | ((unsigned)f2h(v.y) << 16); \
        *reinterpret_cast<unsigned*>(&s_scr[(AB_) + (((k >> 5) * 4 + ((k >> 3) & 3)) * G + g_) * 8 + (k & 7)]) = d; \
    } }

// quarter-split staging: one item (14 VGPRs) in flight at a time -> no spill
#define STAGE_ISSUE(U_) { \
    if (hasN) { \
        const int it = t + (U_) * 256; \
        gs = it / P; ps = it - gs * P; \
        const int s_ = s_st[nxt][gs], c_ = s_st[nxt][gs + 1] - s_; \
        const bool lv = (ps < c_); \
        const float2* xr = reinterpret_cast<const float2*>(x + (size_t)(s_ + ps) * F); \
        _Pragma("unroll") for (int q = 0; q < 7; ++q) { \
            xs[q] = make_float2(0.f, 0.f); \
            if (lv) xs[q] = xr[q]; \
        } \
    } }

#define STAGE_WRITE() { \
    if (hasN) { \
        _Pragma("unroll") for (int q = 0; q < 7; ++q) { \
            const int k = ps * F + q * 2; \
            const unsigned d = (unsigned)f2h(xs[q].x) | ((unsigned)f2h(xs[q].y) << 16); \
            *reinterpret_cast<unsigned*>( \
                &s_scr[nbase + (((k >> 5) * 4 + ((k >> 3) & 3)) * G + gs) * 8 + (k & 7)]) = d; \
        } \
    } }

// ---- fused persistent: tiles pipelined, spill-free quarter staging ----
__global__ __launch_bounds__(256, 2)
void mlp_mfma_kernel(const float* __restrict__ x,
                     const float* __restrict__ b1,
                     const float* __restrict__ b2,
                     const float* __restrict__ b3,
                     const unsigned short* __restrict__ ws,
                     const int* __restrict__ starts,
                     float* __restrict__ out)
{
    __shared__ __align__(16) unsigned short s_scr[36864];   // 73728 B
    __shared__ float s_b1[256], s_b2[128], s_b3[32];
    __shared__ int s_st[2][G + 1];

    const int t    = threadIdx.x;
    const int lane = t & 63;
    const int wv   = t >> 6;          // 0..3
    const int r16  = lane & 15;
    const int kq   = lane >> 4;       // 0..3

    s_b1[t] = b1[t];
    if (t < 128) s_b2[t] = b2[t];
    if (t < 32)  s_b3[t] = (t < 22) ? b3[t] : 0.0f;

    const unsigned short* B1 = ws + W1F / 2;
    const unsigned short* B2 = ws + W2F / 2;
    const unsigned short* B3 = ws + W3F / 2;

    // prologue: ks9 dead cells (k>=308, never gathered) zeroed once per buffer
    if (t < 96) {        // 2 bufs * 48 graphs
        const int c = t / 48, g = t % 48;
        const int b38 = c * A1SZ + ((9 * 4 + 2) * G + g) * 8;
        const int b39 = c * A1SZ + ((9 * 4 + 3) * G + g) * 8;
        *reinterpret_cast<uint2*>(&s_scr[b38 + 4]) = make_uint2(0u, 0u);
        *reinterpret_cast<uint2*>(&s_scr[b39])     = make_uint2(0u, 0u);
        *reinterpret_cast<uint2*>(&s_scr[b39 + 4]) = make_uint2(0u, 0u);
    }

    int tile = blockIdx.x;
    int cur  = 0;
    if (t <= G) s_st[0][t] = starts[tile * G + t];
    __syncthreads();

    // immediate gather of the first tile into A1[0] (slot-major, fixed 1056 items)
    GSLOT_NOW(t,       0, s_st[0])
    GSLOT_NOW(t + 256, 0, s_st[0])
    GSLOT_NOW(t + 512, 0, s_st[0])
    GSLOT_NOW(t + 768, 0, s_st[0])
    if (t < 32) GSLOT_NOW(t + 1024, 0, s_st[0])

    float2 xs[7];
    int gs, ps;

    for (; tile < TILES; tile += NBLKP) {
        const int  g0    = tile * G;
        const int  tileN = tile + NBLKP;
        const bool hasN  = (tileN < TILES);
        const int  nxt   = cur ^ 1;
        const int  abase = cur * A1SZ;
        const int  nbase = nxt * A1SZ;

        half8 Ba[4], Bb[4], Bc[4];
        LOADB1(Ba, 0)
        LOADB1(Bb, 1)
        LOADB1(Bc, 2)
        if (hasN && t <= G) s_st[nxt][t] = starts[tileN * G + t];
        __syncthreads();   // A1[cur] stage-writes + s_st[nxt] visible; orders prev A3 reads

        // ---- GEMM1 with quarter-split staging of tile T+1 interleaved ----
        f32x4 acc[3][4];
        #pragma unroll
        for (int m = 0; m < 3; ++m)
            #pragma unroll
            for (int n = 0; n < 4; ++n) acc[m][n] = (f32x4){0.f, 0.f, 0.f, 0.f};

        STAGE_ISSUE(0)
        COMP1(Ba, 0)  LOADB1(Ba, 3)
        COMP1(Bb, 1)  LOADB1(Bb, 4)
        STAGE_WRITE() STAGE_ISSUE(1)
        COMP1(Bc, 2)  LOADB1(Bc, 5)
        COMP1(Ba, 3)  LOADB1(Ba, 6)
        STAGE_WRITE() STAGE_ISSUE(2)
        COMP1(Bb, 4)  LOADB1(Bb, 7)
        COMP1(Bc, 5)  LOADB1(Bc, 8)
        STAGE_WRITE() STAGE_ISSUE(3)
        COMP1(Ba, 6)  LOADB1(Ba, 9)
        COMP1(Bb, 7)
        STAGE_WRITE()

        half8 Ca[2], Cb[2], Cc[2];
        LOADB2(Ca, 0)
        LOADB2(Cb, 1)
        LOADB2(Cc, 2)
        COMP1(Bc, 8)
        if (hasN && t < 32) GSLOT_NOW(t + 1024, nbase, s_st[nxt])   // tail items
        COMP1(Ba, 9)
        __syncthreads();   // A1[cur] reads done before A2 overwrite

        // epilogue 1: bias+relu -> fp16 -> A2 tiled (@abase, aliases dead A1[cur])
        #pragma unroll
        for (int n = 0; n < 4; ++n) {
            const int j = (wv * 4 + n) * 16 + r16;
            const float bb = s_b1[j];
            const int base = abase + (((j >> 5) * 4 + ((j >> 3) & 3)) * G) * 8 + (j & 7);
            #pragma unroll
            for (int m = 0; m < 3; ++m)
                #pragma unroll
                for (int r = 0; r < 4; ++r) {
                    const int g = m * 16 + kq * 4 + r;
                    s_scr[base + g * 8] = f2h(fmaxf(acc[m][n][r] + bb, 0.0f));
                }
        }
        __syncthreads();

        // ---- GEMM2: [48 x 256] x [256 x 128]; depth-3 ----
        f32x4 acc2[3][2];
        #pragma unroll
        for (int m = 0; m < 3; ++m)
            #pragma unroll
            for (int n = 0; n < 2; ++n) acc2[m][n] = (f32x4){0.f, 0.f, 0.f, 0.f};

        COMP2(Ca, 0)  LOADB2(Ca, 3)
        COMP2(Cb, 1)  LOADB2(Cb, 4)
        COMP2(Cc, 2)  LOADB2(Cc, 5)
        COMP2(Ca, 3)  LOADB2(Ca, 6)
        COMP2(Cb, 4)  LOADB2(Cb, 7)
        COMP2(Cc, 5)
        COMP2(Ca, 6)

        half8 D3[8];
        #pragma unroll
        for (int ks = 0; ks < KS3; ++ks)
            #pragma unroll
            for (int n = 0; n < 2; ++n)
                D3[ks * 2 + n] = *reinterpret_cast<const half8*>(&B3[((ks * JT3 + n) * 64 + lane) * 8]);
        COMP2(Cb, 7)

        // epilogue 2: bias+relu -> fp16 -> A3 @A3O
        #pragma unroll
        for (int n = 0; n < 2; ++n) {
            const int j = (wv * 2 + n) * 16 + r16;
            const float bb = s_b2[j];
            const int base = A3O + (((j >> 5) * 4 + ((j >> 3) & 3)) * G) * 8 + (j & 7);
            #pragma unroll
            for (int m = 0; m < 3; ++m)
                #pragma unroll
                for (int r = 0; r < 4; ++r) {
                    const int g = m * 16 + kq * 4 + r;
                    s_scr[base + g * 8] = f2h(fmaxf(acc2[m][n][r] + bb, 0.0f));
                }
        }
        __syncthreads();   // A3 visible

        // ---- GEMM3: [48 x 128] x [128 x 22(pad32)]; waves 0..2 ----
        if (wv < 3) {
            f32x4 acc3[2];
            acc3[0] = (f32x4){0.f, 0.f, 0.f, 0.f};
            acc3[1] = (f32x4){0.f, 0.f, 0.f, 0.f};
            const int mg = wv * 16;
            #pragma unroll
            for (int ks = 0; ks < KS3; ++ks) {
                const half8 a = *reinterpret_cast<const half8*>(
                    &s_scr[A3O + ((ks * 4 + kq) * G + (mg + r16)) * 8]);
                #pragma unroll
                for (int n = 0; n < 2; ++n)
                    acc3[n] = MFMA16(a, D3[ks * 2 + n], acc3[n]);
            }
            #pragma unroll
            for (int n = 0; n < 2; ++n) {
                const int j = n * 16 + r16;
                if (j < P) {
                    const float bb = s_b3[j];
                    #pragma unroll
                    for (int r = 0; r < 4; ++r) {
                        const int g = mg + kq * 4 + r;
                        if (g0 + g < B_G)
                            out[(size_t)(g0 + g) * P + j] = acc3[n][r] + bb;
                    }
                }
            }
        }
        cur = nxt;
    }
}

extern "C" void kernel_launch(void* const* d_in, const int* in_sizes, int n_in,
                              void* d_out, int out_size, void* d_ws, size_t ws_size,
                              hipStream_t stream) {
    const float* x     = (const float*)d_in[0];
    const int*   batch = (const int*)  d_in[1];
    const float* W1    = (const float*)d_in[2];
    const float* b1    = (const float*)d_in[3];
    const float* W2    = (const float*)d_in[4];
    const float* b2    = (const float*)d_in[5];
    const float* W3    = (const float*)d_in[6];
    const float* b3    = (const float*)d_in[7];
    float* out = (float*)d_out;
    int* starts = (int*)((char*)d_ws + STARTS_OFF);

    aux_kernel<<<dim3(CVT_BLKS + SCAN_BLKS), dim3(256), 0, stream>>>(
        W1, W2, W3, batch, (unsigned*)d_ws, starts);
    mlp_mfma_kernel<<<dim3(NBLKP), dim3(256), 0, stream>>>(
        x, b1, b2, b3, (const unsigned short*)d_ws, starts, out);
}

// Round 20
// 58.154 us; speedup vs baseline: 3.6068x; 2.9033x over previous
//
#include <hip/hip_runtime.h>
#include <hip/hip_fp16.h>

typedef __attribute__((ext_vector_type(8))) _Float16 half8;
typedef __attribute__((ext_vector_type(4))) float f32x4;

namespace {
constexpr int B_G = 131072;     // graphs
constexpr int P   = 22;
constexpr int F   = 14;
constexpr int NF  = 308;        // P*F
constexpr long long N_NODES = (long long)B_G * P;   // 2883584 (divisible by 4)

constexpr int G    = 48;        // graphs per block (LDS ~37KB -> 4 blocks/CU)
constexpr int NBLK = (B_G + G - 1) / G;   // 2731 (last block ragged, guarded)

constexpr int KS1 = 10;         // ceil(308/32)
constexpr int KS2 = 8;          // 256/32
constexpr int KS3 = 4;          // 128/32
constexpr int JT1 = 16;         // 256/16
constexpr int JT2 = 8;          // 128/16
constexpr int JT3 = 2;          // 22 -> pad 32

// d_ws byte offsets; single-term fp16 weights, MFMA B-fragment order (1KB/fragment)
constexpr int W1F = 0;
constexpr int W2F = W1F + KS1 * JT1 * 1024;   // 163840
constexpr int W3F = W2F + KS2 * JT2 * 1024;   // 229376
constexpr int STARTS_OFF = W3F + KS3 * JT3 * 1024;  // 237568 ; (B_G+G+1) ints
constexpr int CVT_DWORDS = (KS1*JT1 + KS2*JT2 + KS3*JT3) * 256;  // 59392
constexpr int CVT_BLKS  = (CVT_DWORDS + 255) / 256;              // 232
constexpr int SCAN_BLKS = (int)((N_NODES + 1023) / 1024);        // 2816 (4 items/thread)
}

__device__ __forceinline__ unsigned short f2h(float v) {
    __half h = __float2half(v);
    return *reinterpret_cast<unsigned short*>(&h);
}

// ---- aux: weight convert (blocks [0,CVT_BLKS)) + starts scan (rest, int4-vectorized) ----
__global__ void aux_kernel(const float* __restrict__ W1,
                           const float* __restrict__ W2,
                           const float* __restrict__ W3,
                           const int* __restrict__ batch,
                           unsigned* __restrict__ ws,
                           int* __restrict__ starts)
{
    const int blk = blockIdx.x;
    const int t   = threadIdx.x;
    if (blk < CVT_BLKS) {
        int p = blk * 256 + t;                    // dword index (2 fp16 elems)
        if (p >= CVT_DWORDS) return;
        const int n1 = KS1 * JT1 * 256;
        const int n2 = KS2 * JT2 * 256;
        const float* W; int NK, NJ, stride, JT, oB, pl;
        if (p < n1)            { W = W1; NK = NF;  NJ = 256; stride = NF;  JT = JT1; oB = W1F/4; pl = p; }
        else if (p < n1 + n2)  { W = W2; NK = 256; NJ = 128; stride = 256; JT = JT2; oB = W2F/4; pl = p - n1; }
        else                   { W = W3; NK = 128; NJ = 22;  stride = 128; JT = JT3; oB = W3F/4; pl = p - n1 - n2; }

        const int e2   = pl & 3;
        const int lane = (pl >> 2) & 63;
        const int jt   = (pl >> 8) % JT;
        const int ks   = (pl >> 8) / JT;
        const int j    = jt * 16 + (lane & 15);
        const int kb   = ks * 32 + (lane >> 4) * 8 + e2 * 2;

        unsigned d = 0;
        #pragma unroll
        for (int q = 0; q < 2; ++q) {
            const int k = kb + q;
            const float v = (k < NK && j < NJ) ? W[j * stride + k] : 0.0f;
            d |= (unsigned)f2h(v) << (16 * q);
        }
        ws[oB + pl] = d;
    } else {
        // starts[g] = lower_bound(batch, g); 4 items/thread via int4 (N_NODES % 4 == 0).
        const long long i0 = (long long)(blk - CVT_BLKS) * 1024 + t * 4;
        if (i0 >= N_NODES) return;
        const int4 b4 = *reinterpret_cast<const int4*>(&batch[i0]);
        int bp = (i0 == 0) ? -1 : batch[i0 - 1];
        const int bs[4] = {b4.x, b4.y, b4.z, b4.w};
        #pragma unroll
        for (int e = 0; e < 4; ++e) {
            for (int g = bp + 1; g <= bs[e]; ++g) starts[g] = (int)(i0 + e);
            bp = bs[e];
        }
        if (i0 + 4 == N_NODES)
            for (int g = bp + 1; g <= B_G + G; ++g) starts[g] = (int)N_NODES;
    }
}

#define MFMA16(A_, B_, C_) __builtin_amdgcn_mfma_f32_16x16x32_f16(A_, B_, C_, 0, 0, 0)

#define LOADB1(H_, KS_) { \
    _Pragma("unroll") for (int n = 0; n < 4; ++n) \
        H_[n] = *reinterpret_cast<const half8*>(&B1[((((KS_) * JT1) + (wv * 4 + n)) * 64 + lane) * 8]); }

#define COMP1(H_, KS_) { \
    half8 a_[3]; \
    _Pragma("unroll") for (int m = 0; m < 3; ++m) \
        a_[m] = *reinterpret_cast<const half8*>(&s_scr[(((KS_) * 4 + kq) * G + (m * 16 + r16)) * 8]); \
    _Pragma("unroll") for (int n = 0; n < 4; ++n) \
        _Pragma("unroll") for (int m = 0; m < 3; ++m) \
            acc[m][n] = MFMA16(a_[m], H_[n], acc[m][n]); }

#define LOADB2(H_, KS_) { \
    _Pragma("unroll") for (int n = 0; n < 2; ++n) \
        H_[n] = *reinterpret_cast<const half8*>(&B2[((((KS_) * JT2) + (wv * 2 + n)) * 64 + lane) * 8]); }

#define COMP2(H_, KS_) { \
    half8 a_[3]; \
    _Pragma("unroll") for (int m = 0; m < 3; ++m) \
        a_[m] = *reinterpret_cast<const half8*>(&s_scr[(((KS_) * 4 + kq) * G + (m * 16 + r16)) * 8]); \
    _Pragma("unroll") for (int n = 0; n < 2; ++n) \
        _Pragma("unroll") for (int m = 0; m < 3; ++m) \
            acc2[m][n] = MFMA16(a_[m], H_[n], acc2[m][n]); }

// node-major gather body (lane i -> node i, coalesced 56B/thread, float4-vectorized)
#define GATHER_BODY(I_) { \
    const int gl = batch[I_] - g0; \
    const int pp = (I_) - s_start[gl]; \
    if (pp < P) { \
        const float* xr = x + (size_t)(I_) * F; \
        const float4 v0 = *reinterpret_cast<const float4*>(xr); \
        const float4 v1 = *reinterpret_cast<const float4*>(xr + 4); \
        const float4 v2 = *reinterpret_cast<const float4*>(xr + 8); \
        const float2 v3 = *reinterpret_cast<const float2*>(xr + 12); \
        const float vv[14] = {v0.x, v0.y, v0.z, v0.w, v1.x, v1.y, v1.z, v1.w, \
                              v2.x, v2.y, v2.z, v2.w, v3.x, v3.y}; \
        _Pragma("unroll") for (int q = 0; q < 7; ++q) { \
            const int k = pp * F + q * 2; \
            const unsigned d = (unsigned)f2h(vv[q * 2]) | ((unsigned)f2h(vv[q * 2 + 1]) << 16); \
            const int off = (((k >> 5) * 4 + ((k >> 3) & 3)) * G + gl) * 8 + (k & 7); \
            *reinterpret_cast<unsigned*>(&s_scr[off]) = d; \
        } \
    } }

#define PIN8(V_) asm volatile("" :: "v"(V_))

// ---- fused: gather -> GEMM1 -> GEMM2 -> GEMM3 ; G=48, 4 blocks/CU ----
__global__ __launch_bounds__(256, 4)
void mlp_mfma_kernel(const float* __restrict__ x,
                     const int* __restrict__ batch,
                     const float* __restrict__ b1,
                     const float* __restrict__ b2,
                     const float* __restrict__ b3,
                     const unsigned short* __restrict__ ws,
                     const int* __restrict__ starts,
                     float* __restrict__ out)
{
    // LDS (ush): A1 = 15360 @0 (k 308->320); A2 = 12288 @0 (aliases dead A1);
    // A3 = 6144 @12288 (disjoint from A2). Total 18432 ush = 36864 B.
    __shared__ __align__(16) unsigned short s_scr[18432];
    __shared__ float s_b1[256], s_b2[128], s_b3[32];
    __shared__ int s_start[G + 1];

    const int t    = threadIdx.x;
    const int g0   = blockIdx.x * G;
    const int lane = t & 63;
    const int wv   = t >> 6;          // 0..3
    const int r16  = lane & 15;
    const int kq   = lane >> 4;       // 0..3

    s_b1[t] = b1[t];
    if (t < 128) s_b2[t] = b2[t];
    if (t < 32)  s_b3[t] = (t < 22) ? b3[t] : 0.0f;

    if (t <= G) s_start[t] = starts[g0 + t];   // precomputed (padded past B_G): no search

    for (int i = t; i < 1920; i += 256)   // pre-zero A1 (30720 B)
        reinterpret_cast<uint4*>(s_scr)[i] = make_uint4(0u, 0u, 0u, 0u);

    const unsigned short* B1 = ws + W1F / 2;
    const unsigned short* B2 = ws + W2F / 2;
    const unsigned short* B3 = ws + W3F / 2;

    half8 Ba[4], Bb[4], Bc[4];
    LOADB1(Ba, 0)                 // 3-stage prefetch; latency hides under gather
    LOADB1(Bb, 1)
    LOADB1(Bc, 2)
    __syncthreads();              // s_start + zeroed A1 visible

    // ---- gather + fp32->fp16 into tiled LDS (node-major, coalesced, float4 loads) ----
    // ~1056 +- 33 nodes/block; unroll 5 (1280) covers +6.8 sigma; tail loop exact.
    const int s0 = s_start[0], s1 = s_start[G];
    #pragma unroll
    for (int u = 0; u < 5; ++u) {
        const int i = s0 + t + u * 256;
        if (i < s1) GATHER_BODY(i)
    }
    for (int i = s0 + t + 5 * 256; i < s1; i += 256)   // tail (covers any node count)
        GATHER_BODY(i)

    PIN8(Ba[0]); PIN8(Ba[1]); PIN8(Ba[2]); PIN8(Ba[3]);
    PIN8(Bb[0]); PIN8(Bb[1]); PIN8(Bb[2]); PIN8(Bb[3]);
    PIN8(Bc[0]); PIN8(Bc[1]); PIN8(Bc[2]); PIN8(Bc[3]);
    __syncthreads();

    // ---- GEMM1: [48 x 308] x [308 x 256]; wave owns cols [wv*64, +64); depth-3 schedule ----
    f32x4 acc[3][4];
    #pragma unroll
    for (int m = 0; m < 3; ++m)
        #pragma unroll
        for (int n = 0; n < 4; ++n) acc[m][n] = (f32x4){0.f, 0.f, 0.f, 0.f};

    COMP1(Ba, 0)  LOADB1(Ba, 3)
    COMP1(Bb, 1)  LOADB1(Bb, 4)
    COMP1(Bc, 2)  LOADB1(Bc, 5)
    COMP1(Ba, 3)  LOADB1(Ba, 6)
    COMP1(Bb, 4)  LOADB1(Bb, 7)
    COMP1(Bc, 5)  LOADB1(Bc, 8)
    COMP1(Ba, 6)  LOADB1(Ba, 9)
    COMP1(Bb, 7)

    half8 Ca[2], Cb[2], Cc[2];
    LOADB2(Ca, 0)                 // GEMM2 stages 0-2 hide under tail of GEMM1 + epilogue 1
    LOADB2(Cb, 1)
    LOADB2(Cc, 2)
    COMP1(Bc, 8)
    COMP1(Ba, 9)
    __syncthreads();   // A1 reads done before A2 overwrite

    // epilogue 1: bias+relu -> fp16 -> A2 tiled (@0, aliases dead A1)
    #pragma unroll
    for (int n = 0; n < 4; ++n) {
        const int j = (wv * 4 + n) * 16 + r16;            // h1 col = GEMM2 k
        const float bb = s_b1[j];
        const int base = (((j >> 5) * 4 + ((j >> 3) & 3)) * G) * 8 + (j & 7);
        #pragma unroll
        for (int m = 0; m < 3; ++m)
            #pragma unroll
            for (int r = 0; r < 4; ++r) {
                const int g = m * 16 + kq * 4 + r;
                s_scr[base + g * 8] = f2h(fmaxf(acc[m][n][r] + bb, 0.0f));
            }
    }
    __syncthreads();

    // ---- GEMM2: [48 x 256] x [256 x 128]; wave owns cols [wv*32, +32); depth-3 ----
    f32x4 acc2[3][2];
    #pragma unroll
    for (int m = 0; m < 3; ++m)
        #pragma unroll
        for (int n = 0; n < 2; ++n) acc2[m][n] = (f32x4){0.f, 0.f, 0.f, 0.f};

    COMP2(Ca, 0)  LOADB2(Ca, 3)
    COMP2(Cb, 1)  LOADB2(Cb, 4)
    COMP2(Cc, 2)  LOADB2(Cc, 5)
    COMP2(Ca, 3)  LOADB2(Ca, 6)
    COMP2(Cb, 4)  LOADB2(Cb, 7)
    COMP2(Cc, 5)
    COMP2(Ca, 6)

    half8 D3[8];                  // all of GEMM3's B; hides under epilogue 2
    #pragma unroll
    for (int ks = 0; ks < KS3; ++ks)
        #pragma unroll
        for (int n = 0; n < 2; ++n)
            D3[ks * 2 + n] = *reinterpret_cast<const half8*>(&B3[((ks * JT3 + n) * 64 + lane) * 8]);
    COMP2(Cb, 7)

    // epilogue 2: bias+relu -> fp16 -> A3 @12288 (disjoint from A2 [0,12288): no barrier)
    #pragma unroll
    for (int n = 0; n < 2; ++n) {
        const int j = (wv * 2 + n) * 16 + r16;            // h2 col = GEMM3 k (0..127)
        const float bb = s_b2[j];
        const int base = 12288 + (((j >> 5) * 4 + ((j >> 3) & 3)) * G) * 8 + (j & 7);
        #pragma unroll
        for (int m = 0; m < 3; ++m)
            #pragma unroll
            for (int r = 0; r < 4; ++r) {
                const int g = m * 16 + kq * 4 + r;
                s_scr[base + g * 8] = f2h(fmaxf(acc2[m][n][r] + bb, 0.0f));
            }
    }
    __syncthreads();

    // ---- GEMM3: [48 x 128] x [128 x 22(pad32)]; waves 0..2 own m-tile wv, both n-tiles ----
    if (wv < 3) {
        f32x4 acc3[2];
        acc3[0] = (f32x4){0.f, 0.f, 0.f, 0.f};
        acc3[1] = (f32x4){0.f, 0.f, 0.f, 0.f};
        const int mg = wv * 16;
        #pragma unroll
        for (int ks = 0; ks < KS3; ++ks) {
            const half8 a = *reinterpret_cast<const half8*>(
                &s_scr[12288 + ((ks * 4 + kq) * G + (mg + r16)) * 8]);
            #pragma unroll
            for (int n = 0; n < 2; ++n)
                acc3[n] = MFMA16(a, D3[ks * 2 + n], acc3[n]);
        }
        #pragma unroll
        for (int n = 0; n < 2; ++n) {
            const int j = n * 16 + r16;
            if (j < P) {
                const float bb = s_b3[j];
                #pragma unroll
                for (int r = 0; r < 4; ++r) {
                    const int g = mg + kq * 4 + r;
                    if (g0 + g < B_G)                      // ragged last block guard
                        out[(size_t)(g0 + g) * P + j] = acc3[n][r] + bb;
                }
            }
        }
    }
}

extern "C" void kernel_launch(void* const* d_in, const int* in_sizes, int n_in,
                              void* d_out, int out_size, void* d_ws, size_t ws_size,
                              hipStream_t stream) {
    const float* x     = (const float*)d_in[0];
    const int*   batch = (const int*)  d_in[1];
    const float* W1    = (const float*)d_in[2];
    const float* b1    = (const float*)d_in[3];
    const float* W2    = (const float*)d_in[4];
    const float* b2    = (const float*)d_in[5];
    const float* W3    = (const float*)d_in[6];
    const float* b3    = (const float*)d_in[7];
    float* out = (float*)d_out;
    int* starts = (int*)((char*)d_ws + STARTS_OFF);

    aux_kernel<<<dim3(CVT_BLKS + SCAN_BLKS), dim3(256), 0, stream>>>(
        W1, W2, W3, batch, (unsigned*)d_ws, starts);
    mlp_mfma_kernel<<<dim3(NBLK), dim3(256), 0, stream>>>(
        x, batch, b1, b2, b3, (const unsigned short*)d_ws, starts, out);
}